// Round 8
// baseline (131.795 us; speedup 1.0000x reference)
//
#include <hip/hip_runtime.h>

// Regime-switching KF — quad-decomposed (4 lanes/series), branch->lane fused
// mixing. Lanes 0..2 own factor row j of the 3x3 regime-1 state; lane 3 is
// aux. The 4 Markov branches' mixing weights are computed with lane b of the
// quad owning branch b (0:11, 1:12, 2:21, 3:22): one exp2/rsq/rcp instead of
// four/three/three. Cross-lane via DPP quad_perm only. 1024 waves -> all
// SIMDs of all 256 CUs busy.

typedef float v2f __attribute__((ext_vector_type(2)));

static __device__ __forceinline__ float frcp(float x)  { return __builtin_amdgcn_rcpf(x); }
static __device__ __forceinline__ float frsq(float x)  { return __builtin_amdgcn_rsqf(x); }
static __device__ __forceinline__ float fexp2(float x) { return __builtin_amdgcn_exp2f(x); }
static __device__ __forceinline__ float flog2(float x) { return __builtin_amdgcn_logf(x); }

template <int CTRL>
static __device__ __forceinline__ float dppf(float x) {
    int i = __float_as_int(x);
    i = __builtin_amdgcn_mov_dpp(i, CTRL, 0xF, 0xF, true);
    return __int_as_float(i);
}
#define ROTL 0xC9   // quad_perm [1,2,0,3]: lane j reads lane j+1 (mod 3)
#define ROTR 0xD2   // quad_perm [2,0,1,3]: lane j reads lane j+2
#define XOR1 0xB1   // quad_perm [1,0,3,2]
#define XOR2 0x4E   // quad_perm [2,3,0,1]
#define BC0  0x00   // broadcast lane 0
#define BC1  0x55
#define BC2  0xAA
#define BC3  0xFF
#define P02  0x88   // quad_perm [0,2,0,2]

static __device__ __forceinline__ float qsum(float x) {
    x += dppf<XOR1>(x);
    x += dppf<XOR2>(x);
    return x;
}
static __device__ __forceinline__ v2f qsum2(v2f x) {
    v2f t;
    t.x = dppf<XOR1>(x.x); t.y = dppf<XOR1>(x.y); x += t;
    t.x = dppf<XOR2>(x.x); t.y = dppf<XOR2>(x.y); x += t;
    return x;
}

#define EPSF   1e-9f
#define L2E    1.4426950408889634f    // log2(e)
#define LN2    0.6931471805599453f
#define L2_2PI_9 23.86346461225016f   // 9*log2(2*pi)
#define C12F   1.00001e-4f            // (1 - 0.9999) + 1e-9
#define P22F   0.99990001f            // 0.9999 + 1e-9
#define QK     (-0.5f * L2E)

__global__ __launch_bounds__(64, 1)
void kf_kernel(const float* __restrict__ y,      // y[n][t][o]
               const float* __restrict__ pBG, const float* __restrict__ pBT,
               const float* __restrict__ pBB, const float* __restrict__ pBW,
               const float* __restrict__ lam1, const float* __restrict__ lam2,
               const float* __restrict__ qd,  const float* __restrict__ rd,
               const float* __restrict__ pG1, const float* __restrict__ pG2,
               float* __restrict__ partial, int N, int Nt)
{
    const int lane = threadIdx.x;
    const int j    = lane & 3;                     // 0..2 = factor row; 3 = aux
    const int sid  = (blockIdx.x * 64 + lane) >> 2;
    const bool valid = (sid < N);
    const bool isRow = (j < 3);
    const int jj = isRow ? j : 0;
    const int rowlen = Nt * 9;                     // 576
    const int nchunk = Nt / 4;

    // ---- wave-uniform setup ----
    const float bg = pBG[0], bt = pBT[0], bb = pBB[0], bw = pBW[0];
    float a[9], l2v[9], id[9], ld[9];
    a[0] = 1.f; a[1] = lam1[0]; a[2] = lam1[1];
    a[3] = 1.f; a[4] = lam1[2]; a[5] = lam1[3];
    a[6] = 1.f; a[7] = lam1[4]; a[8] = lam1[5];
    l2v[0] = 1.f;
    #pragma unroll
    for (int i = 0; i < 8; ++i) l2v[i + 1] = lam2[i];
    float l2detD = 0.f;
    #pragma unroll
    for (int o = 0; o < 9; ++o) {
        float dv = fabsf(rd[o]) + 1.0e-4f + 1.0e-5f;   // R diag + jitter
        id[o] = 1.0f / dv;
        ld[o] = l2v[o] * id[o];
        l2detD += flog2(dv);
    }
    const float q0 = fabsf(qd[0]) + 1e-4f, q1 = fabsf(qd[1]) + 1e-4f;
    const float q2 = fabsf(qd[2]) + 1e-4f, q3 = fabsf(qd[3]) + 1e-4f;
    const float g0 = a[0]*a[0]*id[0] + a[1]*a[1]*id[1] + a[2]*a[2]*id[2];
    const float g1 = a[3]*a[3]*id[3] + a[4]*a[4]*id[4] + a[5]*a[5]*id[5];
    const float g2 = a[6]*a[6]*id[6] + a[7]*a[7]*id[7] + a[8]*a[8]*id[8];
    float h = 0.f;
    #pragma unroll
    for (int o = 0; o < 9; ++o) h += l2v[o] * ld[o];
    const float pk0 = q0 / (1.f + q0 * g0);
    const float pk1 = q1 / (1.f + q1 * g1);
    const float pk2 = q2 / (1.f + q2 * g2);
    const float C12D = C12F * frsq((1.f + q0*g0) * (1.f + q1*g1) * (1.f + q2*g2));
    const float gam1 = pG1[0], w0c = pG2[0], w1c = pG2[1], w2c = pG2[2];
    const float CC = -0.5f * (l2detD + L2_2PI_9);

    // ---- per-lane selected constants (jj = own factor / triplet index) ----
    auto sel3 = [&](float x0, float x1, float x2) {
        float r = (jj == 1) ? x1 : x0;
        return (jj == 2) ? x2 : r;
    };
    const float aO0 = sel3(a[0], a[3], a[6]), aO1 = sel3(a[1], a[4], a[7]), aO2 = sel3(a[2], a[5], a[8]);
    const float iO0 = sel3(id[0], id[3], id[6]), iO1 = sel3(id[1], id[4], id[7]), iO2 = sel3(id[2], id[5], id[8]);
    const float lO0 = sel3(ld[0], ld[3], ld[6]), lO1 = sel3(ld[1], ld[4], ld[7]), lO2 = sel3(ld[2], ld[5], ld[8]);
    const float bS = sel3(bg, bt, bb), bN = sel3(bt, bb, bg), bP = sel3(bb, bg, bt);
    const float gS = sel3(g0, g1, g2), gN = sel3(g1, g2, g0), gP = sel3(g2, g0, g1);
    const float qS = sel3(q0, q1, q2);
    const float pkS = sel3(pk0, pk1, pk2);
    const float wS = sel3(w0c, w1c, w2c);

    auto z3 = [&](float x) { return isRow ? x : 0.0f; };   // mask lane 3

    // ---- state ----
    // pfl_use: lane pattern {pf1, pf2, pf1, pf2} (prob + EPS of origin regime)
    float pfl_use = ((j & 1) == 0 ? 0.99f : 0.01f) + EPSF;
    float seJ = 0.f;                                       // eta1[j]
    float Pr0 = 1000.f, Pr1 = 0.f, Pr2 = 0.f;              // P row j (rel: j, j+1, j+2)
    float sm2 = 0.f, sp2 = 1e-9f;                          // dup
    float acc2 = 0.0f;

    // ---- staging: each lane reads its own 3-obs triplet per step ----
    const float* row = y + (size_t)(valid ? sid : 0) * rowlen + 3 * jj;
    float A[12], B[12];
    auto loadChunk = [&](float (&buf)[12], int c) {
        const float* p = row + c * 36;
        #pragma unroll
        for (int s = 0; s < 4; ++s) {
            buf[s*3+0] = p[s*9+0];
            buf[s*3+1] = p[s*9+1];
            buf[s*3+2] = p[s*9+2];
        }
    };
    loadChunk(A, 0);

    auto step4 = [&](const float (&buf)[12]) {
        #pragma unroll
        for (int s = 0; s < 4; ++s) {
            const float y0 = buf[s*3+0], y1 = buf[s*3+1], y2 = buf[s*3+2];

            // paired quad-reduce: logit part + eta1 sum (both f(seJ))
            v2f r1 = qsum2((v2f){z3(wS * seJ), z3(seJ)});
            float logit = gam1 + r1.x;
            float seS = r1.y;
            float esig = fexp2(-logit * L2E);
            float p11 = frcp(1.f + esig);

            // prediction: mean comp j, S row j (relative), M row j
            float epJ = bS * seJ;
            float S0 = bS*bS*Pr0 + qS;
            float S1 = bS*bN*Pr1;
            float S2 = bS*bP*Pr2;
            float M0 = S0*gS + 1.f;
            float M1 = S1*gN;
            float M2 = S2*gP;

            // innovation on own obs triplet
            float v0 = y0 - aO0*epJ, v1 = y1 - aO1*epJ, v2 = y2 - aO2*epJ;
            float w0v = iO0*v0, w1v = iO1*v1, w2v = iO2*v2;
            float uJ = aO0*w0v + aO1*w1v + aO2*w2v;
            v2f r2 = qsum2((v2f){z3(v0*w0v + v1*w1v + v2*w2v),
                                 z3(lO0*y0 + lO1*y1 + lO2*y2)});
            float vdv = r2.x, yl = r2.y;
            // paired: ydy correction + P-trace (for branch 21 prior variance)
            v2f r3 = qsum2((v2f){z3(epJ * (2.f*uJ + gS*epJ)),
                                 z3(Pr0 + Pr1 + Pr2)});
            float ydy = vdv + r3.x;
            float sP = r3.y;

            // 3x3: gather other M rows, cross-product cofactor row, local det
            float Mn0 = dppf<ROTL>(M0), Mn1 = dppf<ROTL>(M1), Mn2 = dppf<ROTL>(M2);
            float Mp0 = dppf<ROTR>(M0), Mp1 = dppf<ROTR>(M1), Mp2 = dppf<ROTR>(M2);
            float cf0 = Mn0*Mp0 - Mn1*Mp2;
            float cf1 = Mn1*Mp1 - Mn2*Mp0;
            float cf2 = Mn2*Mp2 - Mn0*Mp1;
            float det = M0*cf0 + M1*cf1 + M2*cf2;   // det(M) >= 1 (uniform lanes 0-2)
            float iM  = frcp(det);
            float cn0 = dppf<ROTL>(cf0), cn1 = dppf<ROTL>(cf1), cn2 = dppf<ROTL>(cf2);
            float cp0 = dppf<ROTR>(cf0), cp1 = dppf<ROTR>(cf1), cp2 = dppf<ROTR>(cf2);
            // Ci row j = (S * cof) row j / det  (N = S*cof symmetric)
            float Ci0 = iM * (S0*cf0 + S1*cn2 + S2*cp1);
            float Ci1 = iM * (S0*cf1 + S1*cn0 + S2*cp2);
            float Ci2 = iM * (S0*cf2 + S1*cn1 + S2*cp0);

            // t = Ci u ; branch 12 row parts
            float uN = dppf<ROTL>(uJ), uP = dppf<ROTR>(uJ);
            float tJ = Ci0*uJ + Ci1*uN + Ci2*uP;
            float u12 = uJ + gS * epJ;
            float fJ  = pkS * u12;
            // paired quad-reduce: quad11 part + quad12 part
            v2f r4 = qsum2((v2f){z3(uJ * tJ), z3(pkS * u12 * u12)});
            float quad11 = vdv - r4.x;
            float quad12 = ydy - r4.y;
            float euJ = epJ + tJ;

            // regime-2 twin (dup): rank-1 Sherman-Morrison, branches 21/22
            v2f m2v; m2v.x = seS * (1.f/3.f);       m2v.y = bw * sm2;
            v2f pvv; pvv.x = q3 + sP * (1.f/9.f);   pvv.y = bw*bw*sp2 + q3;
            v2f u1v  = (v2f){yl, yl} - m2v * (v2f){h, h};
            v2f vdav = (v2f){ydy, ydy} - m2v * ((v2f){2.f*yl, 2.f*yl} - m2v * (v2f){h, h});
            v2f denv = (v2f){1.f, 1.f} + pvv * (v2f){h, h};
            v2f idev; idev.x = frcp(denv.x); idev.y = frcp(denv.y);
            v2f puv = pvv * idev;
            v2f quadv = vdav - puv * u1v * u1v;
            v2f euv = m2v + puv * u1v;

            // ---------- branch->lane fused mixing (lane b owns branch b) ----------
            float q11e = QK * quad11, q12e = QK * quad12;
            float q21e = QK * quadv.x, q22e = QK * quadv.y;
            float q_l = (j == 0) ? q11e : (j == 1) ? q12e : (j == 2) ? q21e : q22e;
            float Mq = q_l;
            Mq = fmaxf(Mq, dppf<XOR1>(Mq));
            Mq = fmaxf(Mq, dppf<XOR2>(Mq));                 // max of 4, all lanes
            float det_l = (j == 0) ? det : (j == 2) ? denv.x : (j == 3) ? denv.y : 1.0f;
            // transition-prob factor per lane: {p11+E, C12D, 1-p11+E, P22F}
            float hm = (j == 0) ? (p11 + EPSF)
                     : (j == 1) ? C12D
                     : (j == 2) ? (1.f - p11 + EPSF) : P22F;
            float w_l = pfl_use * hm * frsq(det_l) * fexp2(q_l - Mq);
            float ssum = qsum(w_l);
            acc2 += Mq + flog2(ssum);
            float wn = w_l + dppf<XOR1>(w_l);               // {m1,m1,m2,m2}
            float den_l = fmaf(EPSF, ssum, wn);
            float W_l = w_l * frcp(den_l);                  // {W11,W12,W21,W22}
            float issum = frcp(ssum);
            float pfl = fmaf(wn, issum, EPSF);              // {pf1,pf1,pf2,pf2}
            pfl_use = dppf<P02>(pfl);                       // {pf1,pf2,pf1,pf2}
            float W11 = dppf<BC0>(W_l);
            float W12 = dppf<BC1>(W_l);
            float W21 = dppf<BC2>(W_l);
            float W22 = dppf<BC3>(W_l);

            // collapse regime 1 (row form)
            float neJ = W11*euJ + W12*fJ;
            float daJ = euJ - neJ, dbJ = fJ - neJ;
            float daN = dppf<ROTL>(daJ), daP = dppf<ROTR>(daJ);
            float dbN = dppf<ROTL>(dbJ), dbP = dppf<ROTR>(dbJ);
            Pr0 = W11*(Ci0 + daJ*daJ) + W12*(pkS + dbJ*dbJ);
            Pr1 = W11*(Ci1 + daJ*daN) + W12*(dbJ*dbN);
            Pr2 = W11*(Ci2 + daJ*daP) + W12*(dbJ*dbP);
            seJ = neJ;

            // collapse regime 2 (dup)
            float nm2 = W21*euv.x + W22*euv.y;
            float dc = euv.x - nm2, dd = euv.y - nm2;
            sp2 = W21*(puv.x + dc*dc) + W22*(puv.y + dd*dd);
            sm2 = nm2;
        }
    };

    for (int c = 0; c < nchunk; c += 2) {
        if (c + 1 < nchunk) loadChunk(B, c + 1);
        step4(A);
        if (c + 2 < nchunk) loadChunk(A, c + 2);
        step4(B);
    }

    // one result per series (sublane 0), wave-reduce, one partial per block
    float acc = (valid && j == 0) ? (acc2 + (float)Nt * CC) * LN2 : 0.0f;
    #pragma unroll
    for (int off = 32; off; off >>= 1) acc += __shfl_down(acc, off, 64);
    if (lane == 0) partial[blockIdx.x] = acc;
}

__global__ __launch_bounds__(64)
void reduce_k(const float* __restrict__ part, float* __restrict__ out, int nb)
{
    float s = 0.f;
    for (int i = threadIdx.x; i < nb; i += 64) s += part[i];
    #pragma unroll
    for (int off = 32; off; off >>= 1) s += __shfl_down(s, off, 64);
    if (threadIdx.x == 0) out[0] = s;
}

extern "C" void kernel_launch(void* const* d_in, const int* in_sizes, int n_in,
                              void* d_out, int out_size, void* d_ws, size_t ws_size,
                              hipStream_t stream)
{
    const float* y    = (const float*)d_in[0];
    const float* pBG  = (const float*)d_in[1];
    const float* pBT  = (const float*)d_in[2];
    const float* pBB  = (const float*)d_in[3];
    const float* pBW  = (const float*)d_in[4];
    const float* lam1 = (const float*)d_in[5];
    const float* lam2 = (const float*)d_in[6];
    const float* qd   = (const float*)d_in[7];
    const float* rd   = (const float*)d_in[8];
    const float* pG1  = (const float*)d_in[9];
    const float* pG2  = (const float*)d_in[10];

    const int total = in_sizes[0];
    const int Nt = 64, O = 9;
    const int N = total / (Nt * O);
    const int blocks = (N * 4 + 63) / 64;    // 4 lanes per series

    float* partial = (float*)d_ws;
    kf_kernel<<<blocks, 64, 0, stream>>>(y, pBG, pBT, pBB, pBW, lam1, lam2,
                                         qd, rd, pG1, pG2, partial, N, Nt);
    reduce_k<<<1, 64, 0, stream>>>(partial, (float*)d_out, blocks);
}

// Round 9
// 125.334 us; speedup vs baseline: 1.0516x; 1.0516x over previous
//
#include <hip/hip_runtime.h>

// Regime-switching KF — quad-decomposed: 4 lanes per series.
// Lanes 0..2 of each aligned quad own factor row j (3 obs + row of the 3x3
// state); lane 3 duplicates the scalar work. Cross-lane data moves via DPP
// quad_perm only (no LDS). 65536 threads = 1024 waves -> all 4 SIMDs of all
// 256 CUs busy (vs 1/4 in the 1-lane-per-series version).
// 3x3 inversion in row form: cof_row_j = M_row_{j+1} x M_row_{j+2} (cyclic),
// det = M_row_j . cof_row_j (local), Ci_row_j = (S*cof)_row_j / det
// (N = adj(M)*S = S*cof is symmetric).
// NOTE (R8 post-mortem): do NOT fuse the 4-branch mixing branch->lane; at
// 1 wave/SIMD the serial DPP chain costs more in stalls than the saved ops.

typedef float v2f __attribute__((ext_vector_type(2)));

static __device__ __forceinline__ float frcp(float x)  { return __builtin_amdgcn_rcpf(x); }
static __device__ __forceinline__ float frsq(float x)  { return __builtin_amdgcn_rsqf(x); }
static __device__ __forceinline__ float fexp2(float x) { return __builtin_amdgcn_exp2f(x); }
static __device__ __forceinline__ float flog2(float x) { return __builtin_amdgcn_logf(x); }

template <int CTRL>
static __device__ __forceinline__ float dppf(float x) {
    int i = __float_as_int(x);
    i = __builtin_amdgcn_mov_dpp(i, CTRL, 0xF, 0xF, true);
    return __int_as_float(i);
}
#define ROTL 0xC9   // quad_perm [1,2,0,3]: lane j reads lane j+1 (mod 3)
#define ROTR 0xD2   // quad_perm [2,0,1,3]: lane j reads lane j+2
#define XOR1 0xB1   // quad_perm [1,0,3,2]
#define XOR2 0x4E   // quad_perm [2,3,0,1]

static __device__ __forceinline__ float qsum(float x) {   // sum over the quad
    x += dppf<XOR1>(x);
    x += dppf<XOR2>(x);
    return x;
}

#define EPSF   1e-9f
#define L2E    1.4426950408889634f    // log2(e)
#define LN2    0.6931471805599453f
#define L2_2PI_9 23.86346461225016f   // 9*log2(2*pi)
#define C12F   1.00001e-4f            // (1 - 0.9999) + 1e-9
#define P22F   0.99990001f            // 0.9999 + 1e-9
#define QK     (-0.5f * L2E)

__global__ __launch_bounds__(64, 1)
void kf_kernel(const float* __restrict__ y,      // y[n][t][o]
               const float* __restrict__ pBG, const float* __restrict__ pBT,
               const float* __restrict__ pBB, const float* __restrict__ pBW,
               const float* __restrict__ lam1, const float* __restrict__ lam2,
               const float* __restrict__ qd,  const float* __restrict__ rd,
               const float* __restrict__ pG1, const float* __restrict__ pG2,
               float* __restrict__ partial, int N, int Nt)
{
    const int lane = threadIdx.x;
    const int j    = lane & 3;                     // 0..2 = factor row; 3 = aux
    const int sid  = (blockIdx.x * 64 + lane) >> 2;
    const bool valid = (sid < N);
    const bool isRow = (j < 3);
    const int jj = isRow ? j : 0;
    const int rowlen = Nt * 9;                     // 576
    const int nchunk = Nt / 4;

    // ---- wave-uniform setup ----
    const float bg = pBG[0], bt = pBT[0], bb = pBB[0], bw = pBW[0];
    float a[9], l2v[9], id[9], ld[9];
    a[0] = 1.f; a[1] = lam1[0]; a[2] = lam1[1];
    a[3] = 1.f; a[4] = lam1[2]; a[5] = lam1[3];
    a[6] = 1.f; a[7] = lam1[4]; a[8] = lam1[5];
    l2v[0] = 1.f;
    #pragma unroll
    for (int i = 0; i < 8; ++i) l2v[i + 1] = lam2[i];
    float l2detD = 0.f;
    #pragma unroll
    for (int o = 0; o < 9; ++o) {
        float dv = fabsf(rd[o]) + 1.0e-4f + 1.0e-5f;   // R diag + jitter
        id[o] = 1.0f / dv;
        ld[o] = l2v[o] * id[o];
        l2detD += flog2(dv);
    }
    const float q0 = fabsf(qd[0]) + 1e-4f, q1 = fabsf(qd[1]) + 1e-4f;
    const float q2 = fabsf(qd[2]) + 1e-4f, q3 = fabsf(qd[3]) + 1e-4f;
    const float g0 = a[0]*a[0]*id[0] + a[1]*a[1]*id[1] + a[2]*a[2]*id[2];
    const float g1 = a[3]*a[3]*id[3] + a[4]*a[4]*id[4] + a[5]*a[5]*id[5];
    const float g2 = a[6]*a[6]*id[6] + a[7]*a[7]*id[7] + a[8]*a[8]*id[8];
    float h = 0.f;
    #pragma unroll
    for (int o = 0; o < 9; ++o) h += l2v[o] * ld[o];
    const float pk0 = q0 / (1.f + q0 * g0);
    const float pk1 = q1 / (1.f + q1 * g1);
    const float pk2 = q2 / (1.f + q2 * g2);
    const float C12D = C12F * frsq((1.f + q0*g0) * (1.f + q1*g1) * (1.f + q2*g2));
    const float gam1 = pG1[0], w0c = pG2[0], w1c = pG2[1], w2c = pG2[2];
    const float CC = -0.5f * (l2detD + L2_2PI_9);

    // ---- per-lane selected constants (jj = own factor / triplet index) ----
    auto sel3 = [&](float x0, float x1, float x2) {
        float r = (jj == 1) ? x1 : x0;
        return (jj == 2) ? x2 : r;
    };
    const float aO0 = sel3(a[0], a[3], a[6]), aO1 = sel3(a[1], a[4], a[7]), aO2 = sel3(a[2], a[5], a[8]);
    const float iO0 = sel3(id[0], id[3], id[6]), iO1 = sel3(id[1], id[4], id[7]), iO2 = sel3(id[2], id[5], id[8]);
    const float lO0 = sel3(ld[0], ld[3], ld[6]), lO1 = sel3(ld[1], ld[4], ld[7]), lO2 = sel3(ld[2], ld[5], ld[8]);
    const float bS = sel3(bg, bt, bb), bN = sel3(bt, bb, bg), bP = sel3(bb, bg, bt);
    const float gS = sel3(g0, g1, g2), gN = sel3(g1, g2, g0), gP = sel3(g2, g0, g1);
    const float qS = sel3(q0, q1, q2);
    const float pkS = sel3(pk0, pk1, pk2);
    const float wS = sel3(w0c, w1c, w2c);

    auto z3 = [&](float x) { return isRow ? x : 0.0f; };   // NaN-safe lane-3 mask

    // ---- state ----
    float pf1 = 0.99f + EPSF, pf2 = 0.01f + EPSF;          // dup
    float seJ = 0.f;                                       // eta1[j]
    float Pr0 = 1000.f, Pr1 = 0.f, Pr2 = 0.f;              // P row j (rel: j, j+1, j+2)
    float sm2 = 0.f, sp2 = 1e-9f;                          // dup
    float acc2 = 0.0f;

    // ---- staging: each lane reads its own 3-obs triplet per step ----
    const float* row = y + (size_t)(valid ? sid : 0) * rowlen + 3 * jj;
    float A[12], B[12];
    auto loadChunk = [&](float (&buf)[12], int c) {
        const float* p = row + c * 36;
        #pragma unroll
        for (int s = 0; s < 4; ++s) {
            buf[s*3+0] = p[s*9+0];
            buf[s*3+1] = p[s*9+1];
            buf[s*3+2] = p[s*9+2];
        }
    };
    loadChunk(A, 0);

    auto step4 = [&](const float (&buf)[12]) {
        #pragma unroll
        for (int s = 0; s < 4; ++s) {
            const float y0 = buf[s*3+0], y1 = buf[s*3+1], y2 = buf[s*3+2];

            // HMM transition (logit allreduced; sigmoid dup)
            float logit = gam1 + qsum(z3(wS * seJ));
            float esig = fexp2(-logit * L2E);
            float p11 = frcp(1.f + esig);
            float pf11 = p11 + EPSF, pf21 = 1.f - p11 + EPSF;

            // prediction: mean comp j, S row j (relative), M row j
            float epJ = bS * seJ;
            float S0 = bS*bS*Pr0 + qS;
            float S1 = bS*bN*Pr1;
            float S2 = bS*bP*Pr2;
            float M0 = S0*gS + 1.f;
            float M1 = S1*gN;
            float M2 = S2*gP;

            // innovation on own obs triplet
            float v0 = y0 - aO0*epJ, v1 = y1 - aO1*epJ, v2 = y2 - aO2*epJ;
            float w0v = iO0*v0, w1v = iO1*v1, w2v = iO2*v2;
            float uJ = aO0*w0v + aO1*w1v + aO2*w2v;
            float vdv = qsum(z3(v0*w0v + v1*w1v + v2*w2v));
            float yl  = qsum(z3(lO0*y0 + lO1*y1 + lO2*y2));
            float ydy = vdv + qsum(z3(epJ * (2.f*uJ + gS*epJ)));

            // 3x3: gather other M rows, cross-product cofactor row, local det
            float Mn0 = dppf<ROTL>(M0), Mn1 = dppf<ROTL>(M1), Mn2 = dppf<ROTL>(M2);
            float Mp0 = dppf<ROTR>(M0), Mp1 = dppf<ROTR>(M1), Mp2 = dppf<ROTR>(M2);
            float cf0 = Mn0*Mp0 - Mn1*Mp2;
            float cf1 = Mn1*Mp1 - Mn2*Mp0;
            float cf2 = Mn2*Mp2 - Mn0*Mp1;
            float det = M0*cf0 + M1*cf1 + M2*cf2;   // det(M) >= 1
            float rs  = frsq(det);
            float iM  = rs * rs;                    // 1/det
            float cn0 = dppf<ROTL>(cf0), cn1 = dppf<ROTL>(cf1), cn2 = dppf<ROTL>(cf2);
            float cp0 = dppf<ROTR>(cf0), cp1 = dppf<ROTR>(cf1), cp2 = dppf<ROTR>(cf2);
            // Ci row j = (S * cof) row j / det  (N = S*cof symmetric)
            float Ci0 = iM * (S0*cf0 + S1*cn2 + S2*cp1);
            float Ci1 = iM * (S0*cf1 + S1*cn0 + S2*cp2);
            float Ci2 = iM * (S0*cf2 + S1*cn1 + S2*cp0);

            // t = Ci u ; quad11
            float uN = dppf<ROTL>(uJ), uP = dppf<ROTR>(uJ);
            float tJ = Ci0*uJ + Ci1*uN + Ci2*uP;
            float quad11 = vdv - qsum(z3(uJ * tJ));
            float euJ = epJ + tJ;

            // branch 12 (constant prior)
            float u12 = uJ + gS * epJ;
            float fJ  = pkS * u12;
            float quad12 = ydy - qsum(z3(pkS * u12 * u12));

            // regime-2 twin (duplicated): rank-1 Sherman-Morrison, branches 21/22
            float seS = qsum(z3(seJ));
            float sP  = qsum(z3(Pr0 + Pr1 + Pr2));
            v2f m2v; m2v.x = seS * (1.f/3.f);       m2v.y = bw * sm2;
            v2f pvv; pvv.x = q3 + sP * (1.f/9.f);   pvv.y = bw*bw*sp2 + q3;
            v2f u1v  = (v2f){yl, yl} - m2v * (v2f){h, h};
            v2f vdav = (v2f){ydy, ydy} - m2v * ((v2f){2.f*yl, 2.f*yl} - m2v * (v2f){h, h});
            v2f denv = (v2f){1.f, 1.f} + pvv * (v2f){h, h};
            v2f rvv; rvv.x = frsq(denv.x); rvv.y = frsq(denv.y);
            v2f idev = rvv * rvv;
            v2f puv = pvv * idev;
            v2f quadv = vdav - puv * u1v * u1v;
            v2f euv = m2v + puv * u1v;

            // mixing (dup; dets folded via rsq factors)
            float q11e = QK * quad11, q12e = QK * quad12;
            float q21e = QK * quadv.x, q22e = QK * quadv.y;
            float Mq = fmaxf(fmaxf(q11e, q12e), fmaxf(q21e, q22e));
            float w11 = pf1 * pf11 * rs    * fexp2(q11e - Mq);
            float w12 = pf2 * C12D         * fexp2(q12e - Mq);
            float w21 = pf1 * pf21 * rvv.x * fexp2(q21e - Mq);
            float w22 = pf2 * P22F * rvv.y * fexp2(q22e - Mq);
            float ssum = w11 + w12 + w21 + w22;
            acc2 += Mq + flog2(ssum);
            float pr1n = w11 + w12, pr2n = w21 + w22;
            float den1 = pr1n + EPSF * ssum, den2 = pr2n + EPSF * ssum;
            float inv1 = frcp(den1), inv2 = frcp(den2), issum = frcp(ssum);
            float W11 = w11*inv1, W12 = w12*inv1;
            float W21 = w21*inv2, W22 = w22*inv2;
            pf1 = pr1n * issum + EPSF;
            pf2 = pr2n * issum + EPSF;

            // collapse regime 1 (row form)
            float neJ = W11*euJ + W12*fJ;
            float daJ = euJ - neJ, dbJ = fJ - neJ;
            float daN = dppf<ROTL>(daJ), daP = dppf<ROTR>(daJ);
            float dbN = dppf<ROTL>(dbJ), dbP = dppf<ROTR>(dbJ);
            Pr0 = W11*(Ci0 + daJ*daJ) + W12*(pkS + dbJ*dbJ);
            Pr1 = W11*(Ci1 + daJ*daN) + W12*(dbJ*dbN);
            Pr2 = W11*(Ci2 + daJ*daP) + W12*(dbJ*dbP);
            seJ = neJ;

            // collapse regime 2 (dup)
            float nm2 = W21*euv.x + W22*euv.y;
            float dc = euv.x - nm2, dd = euv.y - nm2;
            sp2 = W21*(puv.x + dc*dc) + W22*(puv.y + dd*dd);
            sm2 = nm2;
        }
    };

    for (int c = 0; c < nchunk; c += 2) {
        if (c + 1 < nchunk) loadChunk(B, c + 1);
        step4(A);
        if (c + 2 < nchunk) loadChunk(A, c + 2);
        step4(B);
    }

    // one result per series (sublane 0), wave-reduce, one partial per block
    float acc = (valid && j == 0) ? (acc2 + (float)Nt * CC) * LN2 : 0.0f;
    #pragma unroll
    for (int off = 32; off; off >>= 1) acc += __shfl_down(acc, off, 64);
    if (lane == 0) partial[blockIdx.x] = acc;
}

__global__ __launch_bounds__(64)
void reduce_k(const float* __restrict__ part, float* __restrict__ out, int nb)
{
    float s = 0.f;
    for (int i = threadIdx.x; i < nb; i += 64) s += part[i];
    #pragma unroll
    for (int off = 32; off; off >>= 1) s += __shfl_down(s, off, 64);
    if (threadIdx.x == 0) out[0] = s;
}

extern "C" void kernel_launch(void* const* d_in, const int* in_sizes, int n_in,
                              void* d_out, int out_size, void* d_ws, size_t ws_size,
                              hipStream_t stream)
{
    const float* y    = (const float*)d_in[0];
    const float* pBG  = (const float*)d_in[1];
    const float* pBT  = (const float*)d_in[2];
    const float* pBB  = (const float*)d_in[3];
    const float* pBW  = (const float*)d_in[4];
    const float* lam1 = (const float*)d_in[5];
    const float* lam2 = (const float*)d_in[6];
    const float* qd   = (const float*)d_in[7];
    const float* rd   = (const float*)d_in[8];
    const float* pG1  = (const float*)d_in[9];
    const float* pG2  = (const float*)d_in[10];

    const int total = in_sizes[0];
    const int Nt = 64, O = 9;
    const int N = total / (Nt * O);
    const int blocks = (N * 4 + 63) / 64;    // 4 lanes per series

    float* partial = (float*)d_ws;
    kf_kernel<<<blocks, 64, 0, stream>>>(y, pBG, pBT, pBB, pBW, lam1, lam2,
                                         qd, rd, pG1, pG2, partial, N, Nt);
    reduce_k<<<1, 64, 0, stream>>>(partial, (float*)d_out, blocks);
}